// Round 2
// baseline (3518.026 us; speedup 1.0000x reference)
//
#include <hip/hip_runtime.h>
#include <hip/hip_bf16.h>

// HRED-style hierarchical GRU + vocab projection, MI355X.
// Structure:
//   1. convert emb/Wih/out_W fp32->bf16 (padded K 300->320, N padded to x128)
//   2. bf16 MFMA GEMM (128x128 tile) computes xg = emb[idx]@Wih^T + bih for
//      enc(u1,u2 merged M=6400) and dec(M=4096), scatter-stored as [t][g][b]
//   3. 116 per-step fp32 GRU kernels (latency-bound; h layout [H][B] coalesced)
//   4. dec hidden states -> bf16 A [4096][320]; projection GEMM M=4096,N=19495,K=320
// fp32 recurrence => only bf16 rounding error from GEMM inputs (~6e-4 absmax).

#define HDIM 300
#define H3   900
#define KP   320
#define NV   19495
#define NVP  19584
#define NB   64
#define TUL  50
#define TTL  64

typedef short short8 __attribute__((ext_vector_type(8)));
typedef float f32x4  __attribute__((ext_vector_type(4)));

__device__ inline unsigned short f32_to_bf16(float f) {
  unsigned int u = __float_as_uint(f);
  u = u + 0x7FFFu + ((u >> 16) & 1u);
  return (unsigned short)(u >> 16);
}

// ---------- fp32 -> bf16 with K padding (cols 300..319 must be pre-zeroed) ----------
__global__ void convert_pad_kernel(const float* __restrict__ src, short* __restrict__ dst, int rows) {
  int total = rows * HDIM;
  for (int i = blockIdx.x * blockDim.x + threadIdx.x; i < total; i += gridDim.x * blockDim.x) {
    int r = i / HDIM, c = i - r * HDIM;
    dst[(long)r * KP + c] = (short)f32_to_bf16(src[i]);
  }
}

// h_dec [t][j][b] fp32 -> A_bf [(b*TT+t)][j] bf16 (K-pad pre-zeroed)
__global__ void convert_A_kernel(const float* __restrict__ hdec, short* __restrict__ dst) {
  int total = TTL * HDIM * NB;
  for (int i = blockIdx.x * blockDim.x + threadIdx.x; i < total; i += gridDim.x * blockDim.x) {
    int t = i / (HDIM * NB);
    int rem = i - t * (HDIM * NB);
    int j = rem / NB;
    int b = rem - j * NB;
    dst[(long)(b * TTL + t) * KP + j] = (short)f32_to_bf16(hdec[i]);
  }
}

// ---------- bf16 MFMA GEMM, 128x128 tile, BK=32, 4 waves (2x2), 4x4 frags/wave ----------
#define GM_PROJ 0
#define GM_XGE  1
#define GM_XGD  2

template <int MODE>
__launch_bounds__(256)
__global__ void mfma_gemm_kernel(const short* __restrict__ A,   // PROJ: A_bf[4096][KP]; XG*: emb_bf[V][KP]
                                 const short* __restrict__ B,   // [Npad][KP] bf16 (row n = weight row n)
                                 const float* __restrict__ bias,
                                 float* __restrict__ C,
                                 const int* __restrict__ idx1,
                                 const int* __restrict__ idx2) {
  __shared__ short Asm[128 * 40];
  __shared__ short Bsm[128 * 40];
  int tid = threadIdx.x;
  int lane = tid & 63, wid = tid >> 6;
  int wm = wid >> 1, wn = wid & 1;
  int m0 = blockIdx.y * 128, n0 = blockIdx.x * 128;

  f32x4 acc[4][4] = {};

  int lrow = tid >> 2, lq = tid & 3;  // staging: 2 rows of 64, 4x16B chunks per row
  long arow[2], brow[2];
#pragma unroll
  for (int h = 0; h < 2; ++h) {
    int m = m0 + lrow + h * 64;
    long rowbase;
    if (MODE == GM_PROJ) {
      rowbase = (long)m * KP;
    } else if (MODE == GM_XGD) {
      rowbase = (long)idx1[m] * KP;          // m = b*64+t, idx flat [B][TT]
    } else {
      int u = m / 3200;
      int rm = m - u * 3200;
      int b = rm / TUL;
      int t = rm - b * TUL;
      int iv = u ? idx2[b * TUL + t] : idx1[b * TUL + t];
      rowbase = (long)iv * KP;
    }
    arow[h] = rowbase + lq * 8;
    brow[h] = (long)(n0 + lrow + h * 64) * KP + lq * 8;
  }

  for (int k0 = 0; k0 < KP; k0 += 32) {
#pragma unroll
    for (int h = 0; h < 2; ++h) {
      *(short8*)&Asm[(lrow + h * 64) * 40 + lq * 8] = *(const short8*)&A[arow[h] + k0];
      *(short8*)&Bsm[(lrow + h * 64) * 40 + lq * 8] = *(const short8*)&B[brow[h] + k0];
    }
    __syncthreads();
    int rlo = lane & 15, khi = (lane >> 4) * 8;
    short8 af[4], bfv[4];
#pragma unroll
    for (int i = 0; i < 4; ++i) af[i]  = *(const short8*)&Asm[(wm * 64 + i * 16 + rlo) * 40 + khi];
#pragma unroll
    for (int i = 0; i < 4; ++i) bfv[i] = *(const short8*)&Bsm[(wn * 64 + i * 16 + rlo) * 40 + khi];
#pragma unroll
    for (int i = 0; i < 4; ++i)
#pragma unroll
      for (int j = 0; j < 4; ++j)
        acc[i][j] = __builtin_amdgcn_mfma_f32_16x16x32_bf16(af[i], bfv[j], acc[i][j], 0, 0, 0);
    __syncthreads();
  }

  // epilogue: C/D layout col=lane&15, row=(lane>>4)*4+reg
  int rhi = (lane >> 4) * 4, cl = lane & 15;
#pragma unroll
  for (int i = 0; i < 4; ++i)
#pragma unroll
    for (int j = 0; j < 4; ++j) {
      int mb = m0 + wm * 64 + i * 16 + rhi;
      int n = n0 + wn * 64 + j * 16 + cl;
#pragma unroll
      for (int r = 0; r < 4; ++r) {
        int m = mb + r;
        float v = acc[i][j][r];
        if (MODE == GM_PROJ) {
          if (n < NV) C[(long)m * NV + n] = v + bias[n];
        } else if (MODE == GM_XGD) {
          if (n < H3) {
            int b = m >> 6, t = m & 63;
            C[(long)t * (H3 * NB) + n * NB + b] = v + bias[n];
          }
        } else {
          if (n < H3) {
            int u = m / 3200;
            int rm = m - u * 3200;
            int b = rm / TUL;
            int t = rm - b * TUL;
            C[(long)t * (H3 * 128) + n * 128 + u * 64 + b] = v + bias[n];
          }
        }
      }
    }
}

// ---------- one GRU step, fp32. h layouts [H][BW]; xg [3H][BW] per step ----------
template <int BW, bool CX>
__launch_bounds__(256)
__global__ void gru_step_kernel(const float* __restrict__ Whh, const float* __restrict__ bhh,
                                const float* __restrict__ xg,
                                const float* __restrict__ Wih, const float* __restrict__ bih,
                                const float* __restrict__ x, int xstride,
                                const float* __restrict__ hin, float* __restrict__ hout,
                                const int* __restrict__ len1, const int* __restrict__ len2, int t) {
  int gt = blockIdx.x * blockDim.x + threadIdx.x;
  if (gt >= HDIM * BW) return;
  int col = gt & (BW - 1);
  int j = gt / BW;

  float hr = bhh[j], hz = bhh[HDIM + j], hn = bhh[2 * HDIM + j];
  const float* wr = Whh + (long)j * HDIM;
  const float* wz = Whh + (long)(HDIM + j) * HDIM;
  const float* wn = Whh + (long)(2 * HDIM + j) * HDIM;
  float xr = 0.f, xz = 0.f, xn = 0.f;
  const float* vr = nullptr;
  const float* vz = nullptr;
  const float* vn = nullptr;
  if (CX) {
    xr = bih[j]; xz = bih[HDIM + j]; xn = bih[2 * HDIM + j];
    vr = Wih + (long)j * HDIM;
    vz = Wih + (long)(HDIM + j) * HDIM;
    vn = Wih + (long)(2 * HDIM + j) * HDIM;
  }

#pragma unroll 4
  for (int k = 0; k < HDIM; ++k) {
    float hv = hin[k * BW + col];
    hr = fmaf(wr[k], hv, hr);
    hz = fmaf(wz[k], hv, hz);
    hn = fmaf(wn[k], hv, hn);
    if (CX) {
      float xv = x[k * xstride + col];
      xr = fmaf(vr[k], xv, xr);
      xz = fmaf(vz[k], xv, xz);
      xn = fmaf(vn[k], xv, xn);
    }
  }
  if (!CX) {
    xr = xg[j * BW + col];
    xz = xg[(HDIM + j) * BW + col];
    xn = xg[(2 * HDIM + j) * BW + col];
  }
  float r = 1.f / (1.f + __expf(-(xr + hr)));
  float z = 1.f / (1.f + __expf(-(xz + hz)));
  float n = tanhf(xn + r * hn);
  float hprev = hin[j * BW + col];
  float hnew = (1.f - z) * n + z * hprev;
  if (len1 != nullptr) {
    int L = (col < 64) ? len1[col] : len2[col - 64];
    if (t >= L) hnew = hprev;
  }
  hout[j * BW + col] = hnew;
}

extern "C" void kernel_launch(void* const* d_in, const int* in_sizes, int n_in,
                              void* d_out, int out_size, void* d_ws, size_t ws_size,
                              hipStream_t stream) {
  const float* emb      = (const float*)d_in[0];
  const float* enc_Wih  = (const float*)d_in[1];
  const float* enc_Whh  = (const float*)d_in[2];
  const float* enc_bih  = (const float*)d_in[3];
  const float* enc_bhh  = (const float*)d_in[4];
  const float* sess_Wih = (const float*)d_in[5];
  const float* sess_Whh = (const float*)d_in[6];
  const float* sess_bih = (const float*)d_in[7];
  const float* sess_bhh = (const float*)d_in[8];
  const float* dec_Wih  = (const float*)d_in[9];
  const float* dec_Whh  = (const float*)d_in[10];
  const float* dec_bih  = (const float*)d_in[11];
  const float* dec_bhh  = (const float*)d_in[12];
  const float* out_W    = (const float*)d_in[13];
  const float* out_b    = (const float*)d_in[14];
  const int* u1_in      = (const int*)d_in[15];
  const int* u1_lens    = (const int*)d_in[16];
  const int* u2_in      = (const int*)d_in[17];
  const int* u2_lens    = (const int*)d_in[18];
  const int* tgt_in     = (const int*)d_in[19];
  float* out = (float*)d_out;

  // ---- workspace carve (256B aligned) ----
  char* w = (char*)d_ws;
  auto alloc = [&](size_t bytes) -> char* {
    char* p = w;
    w += (bytes + 255) & ~(size_t)255;
    return p;
  };
  short* emb_bf  = (short*)alloc((size_t)NV  * KP * 2);  // 12.5 MB
  short* wie_bf  = (short*)alloc((size_t)1024 * KP * 2);
  short* wid_bf  = (short*)alloc((size_t)1024 * KP * 2);
  short* wout_bf = (short*)alloc((size_t)NVP * KP * 2);  // 12.5 MB
  short* a_bf    = (short*)alloc((size_t)4096 * KP * 2);
  char* bf_end = w;
  float* h_enc0 = (float*)alloc((size_t)HDIM * 128 * 4);
  float* h_enc1 = (float*)alloc((size_t)HDIM * 128 * 4);
  float* h_s0   = (float*)alloc((size_t)HDIM * NB * 4);
  float* h_s1   = (float*)alloc((size_t)HDIM * NB * 4);
  char* h_end = w;
  float* xg_enc = (float*)alloc((size_t)TUL * H3 * 128 * 4);  // 23 MB
  float* xg_dec = (float*)alloc((size_t)TTL * H3 * NB * 4);   // 14.7 MB
  float* h_dec  = (float*)alloc((size_t)TTL * HDIM * NB * 4); // 4.9 MB

  // zero bf16 buffers (for K/N padding) and h0 buffers
  hipMemsetAsync(emb_bf, 0, (size_t)(bf_end - (char*)emb_bf), stream);
  hipMemsetAsync(h_enc0, 0, (size_t)(h_end - (char*)h_enc0), stream);

  // conversions
  convert_pad_kernel<<<1024, 256, 0, stream>>>(emb, emb_bf, NV);
  convert_pad_kernel<<<64, 256, 0, stream>>>(enc_Wih, wie_bf, H3);
  convert_pad_kernel<<<64, 256, 0, stream>>>(dec_Wih, wid_bf, H3);
  convert_pad_kernel<<<1024, 256, 0, stream>>>(out_W, wout_bf, NV);

  // xg GEMMs (gathered embeddings)
  {
    dim3 g(8, 50);
    mfma_gemm_kernel<GM_XGE><<<g, 256, 0, stream>>>(emb_bf, wie_bf, enc_bih, xg_enc, u1_in, u2_in);
  }
  {
    dim3 g(8, 32);
    mfma_gemm_kernel<GM_XGD><<<g, 256, 0, stream>>>(emb_bf, wid_bf, dec_bih, xg_dec, tgt_in, nullptr);
  }

  // encoder: u1 (cols 0-63) and u2 (cols 64-127) together, 50 steps
  float* hb[2] = {h_enc0, h_enc1};
  for (int t = 0; t < TUL; ++t) {
    gru_step_kernel<128, false><<<150, 256, 0, stream>>>(
        enc_Whh, enc_bhh, xg_enc + (long)t * H3 * 128,
        nullptr, nullptr, nullptr, 0,
        hb[t & 1], hb[(t + 1) & 1], u1_lens, u2_lens, t);
  }
  float* encf = hb[0];  // 50 even

  // session GRU: 2 steps, input = enc final hidden (x-projection computed inline)
  float* sb[2] = {h_s0, h_s1};
  for (int t = 0; t < 2; ++t) {
    gru_step_kernel<64, true><<<75, 256, 0, stream>>>(
        sess_Whh, sess_bhh, nullptr,
        sess_Wih, sess_bih, encf + t * 64, 128,
        sb[t & 1], sb[(t + 1) & 1], nullptr, nullptr, t);
  }
  float* sessf = sb[0];

  // decoder: 64 steps, no mask; store every h_t
  for (int t = 0; t < TTL; ++t) {
    const float* hin = (t == 0) ? sessf : (h_dec + (long)(t - 1) * HDIM * NB);
    gru_step_kernel<64, false><<<75, 256, 0, stream>>>(
        dec_Whh, dec_bhh, xg_dec + (long)t * H3 * NB,
        nullptr, nullptr, nullptr, 0,
        hin, h_dec + (long)t * HDIM * NB, nullptr, nullptr, t);
  }

  // projection
  convert_A_kernel<<<512, 256, 0, stream>>>(h_dec, a_bf);
  {
    dim3 g(153, 32);
    mfma_gemm_kernel<GM_PROJ><<<g, 256, 0, stream>>>(a_bf, wout_bf, out_b, out, nullptr, nullptr);
  }
}

// Round 6
// 3028.798 us; speedup vs baseline: 1.1615x; 1.1615x over previous
//
#include <hip/hip_runtime.h>
#include <hip/hip_bf16.h>

// HRED-style hierarchical GRU + vocab projection, MI355X.
// v2: fused persistent recurrence kernel (8 WGs, zero cross-WG comm) replaces
// 116 per-step launches. h fp32 in LDS + bf16 shadow for MFMA A; Whh streamed
// bf16 from L2 as MFMA B each step (2-deep pipelined chunks). Dec writes bf16
// h directly into projection-A layout.

#define HDIM 300
#define H3   900
#define KP   320
#define NV   19495
#define NVP  19584
#define NB   64
#define TUL  50
#define TTL  64
#define HS   328   // bf16 h row stride (pad: 2-way-max LDS conflicts)
#define HFS  301   // fp32 h row stride

typedef short short8 __attribute__((ext_vector_type(8)));
typedef float f32x4  __attribute__((ext_vector_type(4)));

__device__ inline unsigned short f32_to_bf16(float f) {
  unsigned int u = __float_as_uint(f);
  u = u + 0x7FFFu + ((u >> 16) & 1u);
  return (unsigned short)(u >> 16);
}

// ---------- fp32 -> bf16 with K padding (cols 300..319 / rows past `rows` pre-zeroed) ----------
__global__ void convert_pad_kernel(const float* __restrict__ src, short* __restrict__ dst, int rows) {
  int total = rows * HDIM;
  for (int i = blockIdx.x * blockDim.x + threadIdx.x; i < total; i += gridDim.x * blockDim.x) {
    int r = i / HDIM, c = i - r * HDIM;
    dst[(long)r * KP + c] = (short)f32_to_bf16(src[i]);
  }
}

// ---------- bf16 MFMA GEMM, 128x128 tile, BK=32, 4 waves (2x2), 4x4 frags/wave ----------
#define GM_PROJ 0
#define GM_XGE  1
#define GM_XGD  2

template <int MODE>
__launch_bounds__(256)
__global__ void mfma_gemm_kernel(const short* __restrict__ A,
                                 const short* __restrict__ B,
                                 const float* __restrict__ bias,
                                 float* __restrict__ C,
                                 const int* __restrict__ idx1,
                                 const int* __restrict__ idx2) {
  __shared__ short Asm[128 * 40];
  __shared__ short Bsm[128 * 40];
  int tid = threadIdx.x;
  int lane = tid & 63, wid = tid >> 6;
  int wm = wid >> 1, wn = wid & 1;
  int m0 = blockIdx.y * 128, n0 = blockIdx.x * 128;

  f32x4 acc[4][4] = {};

  int lrow = tid >> 2, lq = tid & 3;
  long arow[2], brow[2];
#pragma unroll
  for (int h = 0; h < 2; ++h) {
    int m = m0 + lrow + h * 64;
    long rowbase;
    if (MODE == GM_PROJ) {
      rowbase = (long)m * KP;
    } else if (MODE == GM_XGD) {
      rowbase = (long)idx1[m] * KP;
    } else {
      int u = m / 3200;
      int rm = m - u * 3200;
      int b = rm / TUL;
      int t = rm - b * TUL;
      int iv = u ? idx2[b * TUL + t] : idx1[b * TUL + t];
      rowbase = (long)iv * KP;
    }
    arow[h] = rowbase + lq * 8;
    brow[h] = (long)(n0 + lrow + h * 64) * KP + lq * 8;
  }

  for (int k0 = 0; k0 < KP; k0 += 32) {
#pragma unroll
    for (int h = 0; h < 2; ++h) {
      *(short8*)&Asm[(lrow + h * 64) * 40 + lq * 8] = *(const short8*)&A[arow[h] + k0];
      *(short8*)&Bsm[(lrow + h * 64) * 40 + lq * 8] = *(const short8*)&B[brow[h] + k0];
    }
    __syncthreads();
    int rlo = lane & 15, khi = (lane >> 4) * 8;
    short8 af[4], bfv[4];
#pragma unroll
    for (int i = 0; i < 4; ++i) af[i]  = *(const short8*)&Asm[(wm * 64 + i * 16 + rlo) * 40 + khi];
#pragma unroll
    for (int i = 0; i < 4; ++i) bfv[i] = *(const short8*)&Bsm[(wn * 64 + i * 16 + rlo) * 40 + khi];
#pragma unroll
    for (int i = 0; i < 4; ++i)
#pragma unroll
      for (int j = 0; j < 4; ++j)
        acc[i][j] = __builtin_amdgcn_mfma_f32_16x16x32_bf16(af[i], bfv[j], acc[i][j], 0, 0, 0);
    __syncthreads();
  }

  int rhi = (lane >> 4) * 4, cl = lane & 15;
#pragma unroll
  for (int i = 0; i < 4; ++i)
#pragma unroll
    for (int j = 0; j < 4; ++j) {
      int mb = m0 + wm * 64 + i * 16 + rhi;
      int n = n0 + wn * 64 + j * 16 + cl;
#pragma unroll
      for (int r = 0; r < 4; ++r) {
        int m = mb + r;
        float v = acc[i][j][r];
        if (MODE == GM_PROJ) {
          if (n < NV) C[(long)m * NV + n] = v + bias[n];
        } else if (MODE == GM_XGD) {
          if (n < H3) {
            int b = m >> 6, t = m & 63;
            C[(long)t * (H3 * NB) + n * NB + b] = v + bias[n];
          }
        } else {
          if (n < H3) {
            int u = m / 3200;
            int rm = m - u * 3200;
            int b = rm / TUL;
            int t = rm - b * TUL;
            C[(long)t * (H3 * 128) + n * 128 + u * 64 + b] = v + bias[n];
          }
        }
      }
    }
}

// ---------------- fused recurrence ----------------
// Wave wv owns jmod tiles {wv, wv+4, wv+8, wv+12, wv+16} (tile = 16 j's); each
// lane holds gate triplet (j, j+300, j+600) in-register -> gate math local.
// B stream: chunk = (tw,g) = 10 k-iters of one 16-wide j-tile; 2-deep prefetch.
__device__ __forceinline__ void run_chunks(const short* __restrict__ Wb,
                                           const short8 (&af)[10],
                                           f32x4 (&acc)[5][3],
                                           int wv, int lane) {
  int jc = lane & 15;
  int kh = (lane >> 4) * 8;
  short8 bb[3][10];
  auto issue = [&](int c, short8 (&buf)[10]) {
    int tw = c / 3, g = c - tw * 3;
    const short* p = Wb + (long)(g * HDIM + (wv + 4 * tw) * 16 + jc) * KP + kh;
#pragma unroll
    for (int kk = 0; kk < 10; ++kk) buf[kk] = *(const short8*)(p + kk * 32);
  };
  issue(0, bb[0]);
  issue(1, bb[1]);
#pragma unroll
  for (int c = 0; c < 15; ++c) {
    if (c + 2 < 15) issue(c + 2, bb[(c + 2) % 3]);
    int tw = c / 3, g = c - tw * 3;
#pragma unroll
    for (int kk = 0; kk < 10; ++kk)
      acc[tw][g] = __builtin_amdgcn_mfma_f32_16x16x32_bf16(af[kk], bb[c % 3][kk], acc[tw][g], 0, 0, 0);
  }
}

// MODE: 0 enc (M=16: rows 0-7 u1, 8-15 u2; xg global [t][900][128]; len mask)
//       1 dec (M=8; xg global [t][900][64]; writes abf)
//       2 sess (M=8; xg from LDS xgS)
template <int MODE>
__device__ __forceinline__ void gru_fused_step(
    int w, int wv, int lane, int t,
    const short* __restrict__ Wb, const float* __restrict__ xg,
    float* __restrict__ hF, short* __restrict__ hbf,
    const float* __restrict__ bhhL, const float* __restrict__ xgS,
    const int* __restrict__ lensL, short* __restrict__ abf) {
  int jc = lane & 15, kh = (lane >> 4) * 8, mh = lane >> 4;
  short8 af[10];
#pragma unroll
  for (int kk = 0; kk < 10; ++kk)
    af[kk] = *(const short8*)&hbf[jc * HS + kk * 32 + kh];
  __syncthreads();   // all waves have A-frags before anyone rewrites hbf below
  f32x4 acc[5][3];
#pragma unroll
  for (int a = 0; a < 5; ++a)
#pragma unroll
    for (int g = 0; g < 3; ++g) acc[a][g] = (f32x4){0.f, 0.f, 0.f, 0.f};
  run_chunks(Wb, af, acc, wv, lane);
#pragma unroll
  for (int tw = 0; tw < 5; ++tw) {
    int jm = (wv + 4 * tw) * 16 + jc;
    bool jok = jm < HDIM;
    int j = jok ? jm : 0;
    float br = bhhL[j], bz = bhhL[HDIM + j], bn = bhhL[2 * HDIM + j];
#pragma unroll
    for (int r = 0; r < 4; ++r) {
      int m = mh * 4 + r;
      float XR, XZ, XN;
      if (MODE == 0) {
        int col = (m < 8) ? (8 * w + m) : (64 + 8 * w + (m - 8));
        const float* b = xg + ((long)t * H3 + j) * 128 + col;
        XR = b[0]; XZ = b[HDIM * 128]; XN = b[2 * HDIM * 128];
      } else if (MODE == 1) {
        int col = 8 * w + (m & 7);
        const float* b = xg + ((long)t * H3 + j) * NB + col;
        XR = b[0]; XZ = b[HDIM * NB]; XN = b[2 * HDIM * NB];
      } else {
        XR = xgS[(0 * KP + j) * 17 + m];
        XZ = xgS[(1 * KP + j) * 17 + m];
        XN = xgS[(2 * KP + j) * 17 + m];
      }
      float HRv = acc[tw][0][r] + br;
      float HZv = acc[tw][1][r] + bz;
      float HNv = acc[tw][2][r] + bn;
      float rg = 1.f / (1.f + __expf(-(XR + HRv)));
      float zg = 1.f / (1.f + __expf(-(XZ + HZv)));
      float ng = tanhf(XN + rg * HNv);
      float hp = hF[m * HFS + j];
      float hnew = (1.f - zg) * ng + zg * hp;
      if (MODE == 0 && t >= lensL[m]) hnew = hp;
      bool mok = (MODE == 0) || (m < 8);
      if (jok && mok) {
        hF[m * HFS + jm] = hnew;
        short hb = (short)f32_to_bf16(hnew);
        hbf[m * HS + jm] = hb;
        if (MODE == 1) abf[((long)(8 * w + m) * TTL + t) * KP + jm] = hb;
      }
    }
  }
  __syncthreads();   // step complete: hF/hbf consistent for next step
}

__launch_bounds__(256, 1)
__global__ void fused_recurrence_kernel(
    const short* __restrict__ WhhE, const short* __restrict__ WhhSs,
    const short* __restrict__ WihSs, const short* __restrict__ WhhD,
    const float* __restrict__ bhhE_g, const float* __restrict__ bhhS_g,
    const float* __restrict__ bihS_g, const float* __restrict__ bhhD_g,
    const float* __restrict__ xgE, const float* __restrict__ xgD,
    const int* __restrict__ u1l, const int* __restrict__ u2l,
    short* __restrict__ abf) {
  __shared__ float hF1[16 * HFS];
  __shared__ short hb1[16 * HS];
  __shared__ float hF2[16 * HFS];
  __shared__ short hb2[16 * HS];
  __shared__ float xgS[3 * KP * 17];
  __shared__ float bhhL[H3];
  __shared__ int lensL[16];
  int tid = threadIdx.x, lane = tid & 63, wv = tid >> 6, w = blockIdx.x;

  for (int i = tid; i < 16 * HFS; i += 256) { hF1[i] = 0.f; hF2[i] = 0.f; }
  for (int i = tid; i < 16 * HS; i += 256) { hb1[i] = 0; hb2[i] = 0; }
  if (tid < 8) lensL[tid] = u1l[8 * w + tid];
  else if (tid < 16) lensL[tid] = u2l[8 * w + tid - 8];
  for (int i = tid; i < H3; i += 256) bhhL[i] = bhhE_g[i];
  __syncthreads();

  // ===== encoder: u1 (rows 0-7) + u2 (rows 8-15), 50 steps =====
  for (int t = 0; t < TUL; ++t)
    gru_fused_step<0>(w, wv, lane, t, WhhE, xgE, hF1, hb1, bhhL, nullptr, lensL, nullptr);

  // ===== session: 2 steps, x = enc final h (pass1 computes xg into LDS) =====
  for (int i = tid; i < H3; i += 256) bhhL[i] = bhhS_g[i];
  __syncthreads();
  for (int t = 0; t < 2; ++t) {
    {
      int jc = lane & 15, kh = (lane >> 4) * 8, mh = lane >> 4;
      int xrow = 8 * t + (jc & 7);   // A row m<8 -> enc-final h row 8t+m
      short8 af[10];
#pragma unroll
      for (int kk = 0; kk < 10; ++kk)
        af[kk] = *(const short8*)&hb1[xrow * HS + kk * 32 + kh];
      f32x4 acc[5][3];
#pragma unroll
      for (int a = 0; a < 5; ++a)
#pragma unroll
        for (int g = 0; g < 3; ++g) acc[a][g] = (f32x4){0.f, 0.f, 0.f, 0.f};
      run_chunks(WihSs, af, acc, wv, lane);
#pragma unroll
      for (int tw = 0; tw < 5; ++tw) {
        int jm = (wv + 4 * tw) * 16 + jc;
        if (jm < HDIM) {
#pragma unroll
          for (int g = 0; g < 3; ++g) {
            float bi = bihS_g[g * HDIM + jm];
#pragma unroll
            for (int r = 0; r < 4; ++r)
              xgS[(g * KP + jm) * 17 + (mh * 4 + r)] = acc[tw][g][r] + bi;
          }
        }
      }
      __syncthreads();
    }
    gru_fused_step<2>(w, wv, lane, t, WhhSs, nullptr, hF2, hb2, bhhL, xgS, nullptr, nullptr);
  }

  // ===== decoder: 64 steps on h2, writes bf16 h into projection-A layout =====
  for (int i = tid; i < H3; i += 256) bhhL[i] = bhhD_g[i];
  __syncthreads();
  for (int t = 0; t < TTL; ++t)
    gru_fused_step<1>(w, wv, lane, t, WhhD, xgD, hF2, hb2, bhhL, nullptr, nullptr, abf);
}

extern "C" void kernel_launch(void* const* d_in, const int* in_sizes, int n_in,
                              void* d_out, int out_size, void* d_ws, size_t ws_size,
                              hipStream_t stream) {
  const float* emb      = (const float*)d_in[0];
  const float* enc_Wih  = (const float*)d_in[1];
  const float* enc_Whh  = (const float*)d_in[2];
  const float* enc_bih  = (const float*)d_in[3];
  const float* enc_bhh  = (const float*)d_in[4];
  const float* sess_Wih = (const float*)d_in[5];
  const float* sess_Whh = (const float*)d_in[6];
  const float* sess_bih = (const float*)d_in[7];
  const float* sess_bhh = (const float*)d_in[8];
  const float* dec_Wih  = (const float*)d_in[9];
  const float* dec_Whh  = (const float*)d_in[10];
  const float* dec_bih  = (const float*)d_in[11];
  const float* dec_bhh  = (const float*)d_in[12];
  const float* out_W    = (const float*)d_in[13];
  const float* out_b    = (const float*)d_in[14];
  const int* u1_in      = (const int*)d_in[15];
  const int* u1_lens    = (const int*)d_in[16];
  const int* u2_in      = (const int*)d_in[17];
  const int* u2_lens    = (const int*)d_in[18];
  const int* tgt_in     = (const int*)d_in[19];
  float* out = (float*)d_out;

  char* w = (char*)d_ws;
  auto alloc = [&](size_t bytes) -> char* {
    char* p = w;
    w += (bytes + 255) & ~(size_t)255;
    return p;
  };
  short* emb_bf  = (short*)alloc((size_t)NV  * KP * 2);
  short* wie_bf  = (short*)alloc((size_t)1024 * KP * 2);
  short* wid_bf  = (short*)alloc((size_t)1024 * KP * 2);
  short* wout_bf = (short*)alloc((size_t)NVP * KP * 2);
  short* a_bf    = (short*)alloc((size_t)4096 * KP * 2);
  short* whhE_bf = (short*)alloc((size_t)960 * KP * 2);
  short* whhS_bf = (short*)alloc((size_t)960 * KP * 2);
  short* wihS_bf = (short*)alloc((size_t)960 * KP * 2);
  short* whhD_bf = (short*)alloc((size_t)960 * KP * 2);
  char* bf_end = w;
  float* xg_enc = (float*)alloc((size_t)TUL * H3 * 128 * 4);
  float* xg_dec = (float*)alloc((size_t)TTL * H3 * NB * 4);

  // zero all bf16 buffers (K/N/row padding reads as 0)
  hipMemsetAsync(emb_bf, 0, (size_t)(bf_end - (char*)emb_bf), stream);

  // conversions
  convert_pad_kernel<<<1024, 256, 0, stream>>>(emb, emb_bf, NV);
  convert_pad_kernel<<<64, 256, 0, stream>>>(enc_Wih, wie_bf, H3);
  convert_pad_kernel<<<64, 256, 0, stream>>>(dec_Wih, wid_bf, H3);
  convert_pad_kernel<<<1024, 256, 0, stream>>>(out_W, wout_bf, NV);
  convert_pad_kernel<<<64, 256, 0, stream>>>(enc_Whh, whhE_bf, H3);
  convert_pad_kernel<<<64, 256, 0, stream>>>(sess_Whh, whhS_bf, H3);
  convert_pad_kernel<<<64, 256, 0, stream>>>(sess_Wih, wihS_bf, H3);
  convert_pad_kernel<<<64, 256, 0, stream>>>(dec_Whh, whhD_bf, H3);

  // xg GEMMs (gathered embeddings)
  {
    dim3 g(8, 50);
    mfma_gemm_kernel<GM_XGE><<<g, 256, 0, stream>>>(emb_bf, wie_bf, enc_bih, xg_enc, u1_in, u2_in);
  }
  {
    dim3 g(8, 32);
    mfma_gemm_kernel<GM_XGD><<<g, 256, 0, stream>>>(emb_bf, wid_bf, dec_bih, xg_dec, tgt_in, nullptr);
  }

  // fused recurrence: enc(50) + sess(2) + dec(64), one launch, 8 WGs
  fused_recurrence_kernel<<<8, 256, 0, stream>>>(
      whhE_bf, whhS_bf, wihS_bf, whhD_bf,
      enc_bhh, sess_bhh, sess_bih, dec_bhh,
      xg_enc, xg_dec, u1_lens, u2_lens, a_bf);

  // projection
  {
    dim3 g(153, 32);
    mfma_gemm_kernel<GM_PROJ><<<g, 256, 0, stream>>>(a_bf, wout_bf, out_b, out, nullptr, nullptr);
  }
}

// Round 7
// 2912.880 us; speedup vs baseline: 1.2077x; 1.0398x over previous
//
#include <hip/hip_runtime.h>
#include <hip/hip_bf16.h>

// HRED-style hierarchical GRU + vocab projection, MI355X.
// v3: recurrence rebuilt after r6 counters showed spill (WRITE 9.7MB) + 1 wave/SIMD
// latency binding (per-CU VALUBusy 12%). Now 8 WGs x 512 thr (2 waves/SIMD,
// SIMD-balanced j-tile split), 3x5-kblock prefetch rotation (60 VGPR), xg gate
// inputs hoisted to step start, double-buffered bf16 h => 1 barrier/step.

#define HDIM 300
#define H3   900
#define KP   320
#define NV   19495
#define NVP  19584
#define NB   64
#define TUL  50
#define TTL  64
#define HS   328   // bf16 h row stride
#define HFS  301   // fp32 h row stride

typedef short short8 __attribute__((ext_vector_type(8)));
typedef float f32x4  __attribute__((ext_vector_type(4)));

__device__ inline unsigned short f32_to_bf16(float f) {
  unsigned int u = __float_as_uint(f);
  u = u + 0x7FFFu + ((u >> 16) & 1u);
  return (unsigned short)(u >> 16);
}

// ---------- fp32 -> bf16 with K padding (pad pre-zeroed) ----------
__global__ void convert_pad_kernel(const float* __restrict__ src, short* __restrict__ dst, int rows) {
  int total = rows * HDIM;
  for (int i = blockIdx.x * blockDim.x + threadIdx.x; i < total; i += gridDim.x * blockDim.x) {
    int r = i / HDIM, c = i - r * HDIM;
    dst[(long)r * KP + c] = (short)f32_to_bf16(src[i]);
  }
}

// ---------- bf16 MFMA GEMM, 128x128 tile, BK=32, 4 waves (2x2), 4x4 frags/wave ----------
#define GM_PROJ 0
#define GM_XGE  1
#define GM_XGD  2

template <int MODE>
__launch_bounds__(256)
__global__ void mfma_gemm_kernel(const short* __restrict__ A,
                                 const short* __restrict__ B,
                                 const float* __restrict__ bias,
                                 float* __restrict__ C,
                                 const int* __restrict__ idx1,
                                 const int* __restrict__ idx2) {
  __shared__ short Asm[128 * 40];
  __shared__ short Bsm[128 * 40];
  int tid = threadIdx.x;
  int lane = tid & 63, wid = tid >> 6;
  int wm = wid >> 1, wn = wid & 1;
  int m0 = blockIdx.y * 128, n0 = blockIdx.x * 128;

  f32x4 acc[4][4] = {};

  int lrow = tid >> 2, lq = tid & 3;
  long arow[2], brow[2];
#pragma unroll
  for (int h = 0; h < 2; ++h) {
    int m = m0 + lrow + h * 64;
    long rowbase;
    if (MODE == GM_PROJ) {
      rowbase = (long)m * KP;
    } else if (MODE == GM_XGD) {
      rowbase = (long)idx1[m] * KP;
    } else {
      int u = m / 3200;
      int rm = m - u * 3200;
      int b = rm / TUL;
      int t = rm - b * TUL;
      int iv = u ? idx2[b * TUL + t] : idx1[b * TUL + t];
      rowbase = (long)iv * KP;
    }
    arow[h] = rowbase + lq * 8;
    brow[h] = (long)(n0 + lrow + h * 64) * KP + lq * 8;
  }

  for (int k0 = 0; k0 < KP; k0 += 32) {
#pragma unroll
    for (int h = 0; h < 2; ++h) {
      *(short8*)&Asm[(lrow + h * 64) * 40 + lq * 8] = *(const short8*)&A[arow[h] + k0];
      *(short8*)&Bsm[(lrow + h * 64) * 40 + lq * 8] = *(const short8*)&B[brow[h] + k0];
    }
    __syncthreads();
    int rlo = lane & 15, khi = (lane >> 4) * 8;
    short8 af[4], bfv[4];
#pragma unroll
    for (int i = 0; i < 4; ++i) af[i]  = *(const short8*)&Asm[(wm * 64 + i * 16 + rlo) * 40 + khi];
#pragma unroll
    for (int i = 0; i < 4; ++i) bfv[i] = *(const short8*)&Bsm[(wn * 64 + i * 16 + rlo) * 40 + khi];
#pragma unroll
    for (int i = 0; i < 4; ++i)
#pragma unroll
      for (int j = 0; j < 4; ++j)
        acc[i][j] = __builtin_amdgcn_mfma_f32_16x16x32_bf16(af[i], bfv[j], acc[i][j], 0, 0, 0);
    __syncthreads();
  }

  int rhi = (lane >> 4) * 4, cl = lane & 15;
#pragma unroll
  for (int i = 0; i < 4; ++i)
#pragma unroll
    for (int j = 0; j < 4; ++j) {
      int mb = m0 + wm * 64 + i * 16 + rhi;
      int n = n0 + wn * 64 + j * 16 + cl;
#pragma unroll
      for (int r = 0; r < 4; ++r) {
        int m = mb + r;
        float v = acc[i][j][r];
        if (MODE == GM_PROJ) {
          if (n < NV) C[(long)m * NV + n] = v + bias[n];
        } else if (MODE == GM_XGD) {
          if (n < H3) {
            int b = m >> 6, t = m & 63;
            C[(long)t * (H3 * NB) + n * NB + b] = v + bias[n];
          }
        } else {
          if (n < H3) {
            int u = m / 3200;
            int rm = m - u * 3200;
            int b = rm / TUL;
            int t = rm - b * TUL;
            C[(long)t * (H3 * 128) + n * 128 + u * 64 + b] = v + bias[n];
          }
        }
      }
    }
}

// ---------------- fused recurrence (v3: 8 waves) ----------------
// Wave wv owns j-tiles {wv, wv+8} (+ {16+wv} for wv<4) => 5 tiles per SIMD.
// B-stream rotation: half-chunk = (tile,gate,5 k-blocks) = 20 VGPR, 3 slots.
template <int NT>
__device__ __forceinline__ void run_chunks8(const short* __restrict__ Wb,
                                            const short8 (&af)[10],
                                            f32x4 (&acc)[NT][3],
                                            const int (&tiles)[3], int lane) {
  int jc = lane & 15;
  int kh = (lane >> 4) * 8;
  short8 bb[3][5];
  auto issue = [&](int hc, short8 (&buf)[5]) {
    int c = hc >> 1, hh = hc & 1;
    int ti = c / 3, g = c - ti * 3;
    const short* p = Wb + (long)(g * HDIM + tiles[ti] * 16 + jc) * KP + hh * 160 + kh;
#pragma unroll
    for (int kk = 0; kk < 5; ++kk) buf[kk] = *(const short8*)(p + kk * 32);
  };
  issue(0, bb[0]);
  issue(1, bb[1]);
#pragma unroll
  for (int hc = 0; hc < NT * 6; ++hc) {
    if (hc + 2 < NT * 6) issue(hc + 2, bb[(hc + 2) % 3]);
    int c = hc >> 1, hh = hc & 1, ti = c / 3, g = c - ti * 3;
#pragma unroll
    for (int kk = 0; kk < 5; ++kk)
      acc[ti][g] = __builtin_amdgcn_mfma_f32_16x16x32_bf16(af[hh * 5 + kk], bb[hc % 3][kk], acc[ti][g], 0, 0, 0);
  }
}

// MODE: 0 enc (M=16: rows 0-7 u1, 8-15 u2; xg [t][900][128]; len mask)
//       1 dec (M=8; xg [t][900][64]; writes abf)
//       2 sess (M=8; xgv precomputed by caller)
// No barriers inside (caller syncs after wave-uniform NT branch converges).
template <int NT, int MODE>
__device__ __forceinline__ void gru_step8(
    int w, int lane, const int (&tiles)[3], int t,
    const short* __restrict__ Wb, const float* __restrict__ xg,
    float (&xgv)[3][3][4],
    float* __restrict__ hF, const short* __restrict__ hbf_r, short* __restrict__ hbf_w,
    const float* __restrict__ bhhL, const int* __restrict__ lensL,
    short* __restrict__ abf) {
  int jc = lane & 15, kh = (lane >> 4) * 8, mh = lane >> 4;
  // hoisted xg gate-input loads: issue first, land during MFMA phase
  if (MODE != 2) {
#pragma unroll
    for (int ti = 0; ti < NT; ++ti) {
      int jm = tiles[ti] * 16 + jc;
      int j = (jm < HDIM) ? jm : 0;
#pragma unroll
      for (int g = 0; g < 3; ++g) {
        const float* p = xg + ((long)t * H3 + g * HDIM + j) * (MODE == 0 ? 128 : NB);
#pragma unroll
        for (int r = 0; r < 4; ++r) {
          int m = mh * 4 + r;
          int col = (MODE == 0) ? ((m < 8) ? (8 * w + m) : (64 + 8 * w + (m - 8)))
                                : (8 * w + (m & 7));
          xgv[ti][g][r] = p[col];
        }
      }
    }
  }
  short8 af[10];
#pragma unroll
  for (int kk = 0; kk < 10; ++kk)
    af[kk] = *(const short8*)&hbf_r[jc * HS + kk * 32 + kh];
  f32x4 acc[NT][3];
#pragma unroll
  for (int a = 0; a < NT; ++a)
#pragma unroll
    for (int g = 0; g < 3; ++g) acc[a][g] = (f32x4){0.f, 0.f, 0.f, 0.f};
  run_chunks8<NT>(Wb, af, acc, tiles, lane);
#pragma unroll
  for (int ti = 0; ti < NT; ++ti) {
    int jm = tiles[ti] * 16 + jc;
    bool jok = jm < HDIM;
    int j = jok ? jm : 0;
    float br = bhhL[j], bz = bhhL[HDIM + j], bn = bhhL[2 * HDIM + j];
#pragma unroll
    for (int r = 0; r < 4; ++r) {
      int m = mh * 4 + r;
      float HRv = acc[ti][0][r] + br;
      float HZv = acc[ti][1][r] + bz;
      float HNv = acc[ti][2][r] + bn;
      float rg = 1.f / (1.f + __expf(-(xgv[ti][0][r] + HRv)));
      float zg = 1.f / (1.f + __expf(-(xgv[ti][1][r] + HZv)));
      float ng = tanhf(xgv[ti][2][r] + rg * HNv);
      float hp = hF[m * HFS + j];
      float hnew = (1.f - zg) * ng + zg * hp;
      if (MODE == 0 && t >= lensL[m]) hnew = hp;
      bool mok = (MODE == 0) || (m < 8);
      if (jok && mok) {
        hF[m * HFS + jm] = hnew;
        short hb = (short)f32_to_bf16(hnew);
        hbf_w[m * HS + jm] = hb;
        if (MODE == 1) abf[((long)(8 * w + m) * TTL + t) * KP + jm] = hb;
      }
    }
  }
}

// session x-projection: xg = encfinal_h @ WihS^T + bihS, kept in registers
template <int NT>
__device__ __forceinline__ void sess_xg8(
    int lane, const int (&tiles)[3], int t,
    const short* __restrict__ WihSs, const short* __restrict__ hb1f,
    const float* __restrict__ bihS_g, float (&xgv)[3][3][4]) {
  int jc = lane & 15, kh = (lane >> 4) * 8;
  int xrow = 8 * t + (jc & 7);   // enc-final h row for sess input t
  short8 af[10];
#pragma unroll
  for (int kk = 0; kk < 10; ++kk)
    af[kk] = *(const short8*)&hb1f[xrow * HS + kk * 32 + kh];
  f32x4 acc[NT][3];
#pragma unroll
  for (int a = 0; a < NT; ++a)
#pragma unroll
    for (int g = 0; g < 3; ++g) acc[a][g] = (f32x4){0.f, 0.f, 0.f, 0.f};
  run_chunks8<NT>(WihSs, af, acc, tiles, lane);
#pragma unroll
  for (int ti = 0; ti < NT; ++ti) {
    int jm = tiles[ti] * 16 + jc;
    int j = (jm < HDIM) ? jm : 0;
#pragma unroll
    for (int g = 0; g < 3; ++g) {
      float bi = bihS_g[g * HDIM + j];
#pragma unroll
      for (int r = 0; r < 4; ++r) xgv[ti][g][r] = acc[ti][g][r] + bi;
    }
  }
}

__launch_bounds__(512, 2)
__global__ void fused_recurrence_kernel(
    const short* __restrict__ WhhE, const short* __restrict__ WhhSs,
    const short* __restrict__ WihSs, const short* __restrict__ WhhD,
    const float* __restrict__ bhhE_g, const float* __restrict__ bhhS_g,
    const float* __restrict__ bihS_g, const float* __restrict__ bhhD_g,
    const float* __restrict__ xgE, const float* __restrict__ xgD,
    const int* __restrict__ u1l, const int* __restrict__ u2l,
    short* __restrict__ abf) {
  __shared__ float hF1[16 * HFS];
  __shared__ short hb1[2][16 * HS];
  __shared__ float hF2[16 * HFS];
  __shared__ short hb2[2][16 * HS];
  __shared__ float bhhA[3][H3];
  __shared__ int lensL[16];
  int tid = threadIdx.x, lane = tid & 63, wv = tid >> 6, w = blockIdx.x;

  for (int i = tid; i < 16 * HFS; i += 512) { hF1[i] = 0.f; hF2[i] = 0.f; }
  for (int i = tid; i < 16 * HS; i += 512) { hb1[0][i] = 0; hb1[1][i] = 0; hb2[0][i] = 0; hb2[1][i] = 0; }
  if (tid < 8) lensL[tid] = u1l[8 * w + tid];
  else if (tid < 16) lensL[tid] = u2l[8 * w + tid - 8];
  for (int i = tid; i < H3; i += 512) {
    bhhA[0][i] = bhhE_g[i]; bhhA[1][i] = bhhS_g[i]; bhhA[2][i] = bhhD_g[i];
  }
  __syncthreads();

  int tiles[3] = {wv, wv + 8, 16 + (wv & 3)};
  bool n3 = wv < 4;
  float xgv[3][3][4];

  // ===== encoder: 50 steps, M=16 (u1 rows 0-7, u2 rows 8-15) =====
  for (int t = 0; t < TUL; ++t) {
    if (n3) gru_step8<3, 0>(w, lane, tiles, t, WhhE, xgE, xgv, hF1, hb1[t & 1], hb1[(t + 1) & 1], bhhA[0], lensL, nullptr);
    else    gru_step8<2, 0>(w, lane, tiles, t, WhhE, xgE, xgv, hF1, hb1[t & 1], hb1[(t + 1) & 1], bhhA[0], lensL, nullptr);
    __syncthreads();
  }

  // ===== session: 2 steps (enc final h in hb1[0]) =====
  for (int t = 0; t < 2; ++t) {
    if (n3) {
      sess_xg8<3>(lane, tiles, t, WihSs, hb1[0], bihS_g, xgv);
      gru_step8<3, 2>(w, lane, tiles, t, WhhSs, nullptr, xgv, hF2, hb2[t & 1], hb2[(t + 1) & 1], bhhA[1], nullptr, nullptr);
    } else {
      sess_xg8<2>(lane, tiles, t, WihSs, hb1[0], bihS_g, xgv);
      gru_step8<2, 2>(w, lane, tiles, t, WhhSs, nullptr, xgv, hF2, hb2[t & 1], hb2[(t + 1) & 1], bhhA[1], nullptr, nullptr);
    }
    __syncthreads();
  }

  // ===== decoder: 64 steps, writes bf16 h into projection-A layout =====
  for (int t = 0; t < TTL; ++t) {
    if (n3) gru_step8<3, 1>(w, lane, tiles, t, WhhD, xgD, xgv, hF2, hb2[t & 1], hb2[(t + 1) & 1], bhhA[2], nullptr, abf);
    else    gru_step8<2, 1>(w, lane, tiles, t, WhhD, xgD, xgv, hF2, hb2[t & 1], hb2[(t + 1) & 1], bhhA[2], nullptr, abf);
    __syncthreads();
  }
}

extern "C" void kernel_launch(void* const* d_in, const int* in_sizes, int n_in,
                              void* d_out, int out_size, void* d_ws, size_t ws_size,
                              hipStream_t stream) {
  const float* emb      = (const float*)d_in[0];
  const float* enc_Wih  = (const float*)d_in[1];
  const float* enc_Whh  = (const float*)d_in[2];
  const float* enc_bih  = (const float*)d_in[3];
  const float* enc_bhh  = (const float*)d_in[4];
  const float* sess_Wih = (const float*)d_in[5];
  const float* sess_Whh = (const float*)d_in[6];
  const float* sess_bih = (const float*)d_in[7];
  const float* sess_bhh = (const float*)d_in[8];
  const float* dec_Wih  = (const float*)d_in[9];
  const float* dec_Whh  = (const float*)d_in[10];
  const float* dec_bih  = (const float*)d_in[11];
  const float* dec_bhh  = (const float*)d_in[12];
  const float* out_W    = (const float*)d_in[13];
  const float* out_b    = (const float*)d_in[14];
  const int* u1_in      = (const int*)d_in[15];
  const int* u1_lens    = (const int*)d_in[16];
  const int* u2_in      = (const int*)d_in[17];
  const int* u2_lens    = (const int*)d_in[18];
  const int* tgt_in     = (const int*)d_in[19];
  float* out = (float*)d_out;

  char* w = (char*)d_ws;
  auto alloc = [&](size_t bytes) -> char* {
    char* p = w;
    w += (bytes + 255) & ~(size_t)255;
    return p;
  };
  short* emb_bf  = (short*)alloc((size_t)NV  * KP * 2);
  short* wie_bf  = (short*)alloc((size_t)1024 * KP * 2);
  short* wid_bf  = (short*)alloc((size_t)1024 * KP * 2);
  short* wout_bf = (short*)alloc((size_t)NVP * KP * 2);
  short* a_bf    = (short*)alloc((size_t)4096 * KP * 2);
  short* whhE_bf = (short*)alloc((size_t)960 * KP * 2);
  short* whhS_bf = (short*)alloc((size_t)960 * KP * 2);
  short* wihS_bf = (short*)alloc((size_t)960 * KP * 2);
  short* whhD_bf = (short*)alloc((size_t)960 * KP * 2);
  char* bf_end = w;
  float* xg_enc = (float*)alloc((size_t)TUL * H3 * 128 * 4);
  float* xg_dec = (float*)alloc((size_t)TTL * H3 * NB * 4);

  // zero all bf16 buffers (K/N/row padding reads as 0)
  hipMemsetAsync(emb_bf, 0, (size_t)(bf_end - (char*)emb_bf), stream);

  // conversions
  convert_pad_kernel<<<1024, 256, 0, stream>>>(emb, emb_bf, NV);
  convert_pad_kernel<<<64, 256, 0, stream>>>(enc_Wih, wie_bf, H3);
  convert_pad_kernel<<<64, 256, 0, stream>>>(dec_Wih, wid_bf, H3);
  convert_pad_kernel<<<1024, 256, 0, stream>>>(out_W, wout_bf, NV);
  convert_pad_kernel<<<64, 256, 0, stream>>>(enc_Whh, whhE_bf, H3);
  convert_pad_kernel<<<64, 256, 0, stream>>>(sess_Whh, whhS_bf, H3);
  convert_pad_kernel<<<64, 256, 0, stream>>>(sess_Wih, wihS_bf, H3);
  convert_pad_kernel<<<64, 256, 0, stream>>>(dec_Whh, whhD_bf, H3);

  // xg GEMMs (gathered embeddings)
  {
    dim3 g(8, 50);
    mfma_gemm_kernel<GM_XGE><<<g, 256, 0, stream>>>(emb_bf, wie_bf, enc_bih, xg_enc, u1_in, u2_in);
  }
  {
    dim3 g(8, 32);
    mfma_gemm_kernel<GM_XGD><<<g, 256, 0, stream>>>(emb_bf, wid_bf, dec_bih, xg_dec, tgt_in, nullptr);
  }

  // fused recurrence: enc(50) + sess(2) + dec(64), one launch, 8 WGs x 512 thr
  fused_recurrence_kernel<<<8, 512, 0, stream>>>(
      whhE_bf, whhS_bf, wihS_bf, whhD_bf,
      enc_bhh, sess_bhh, sess_bih, dec_bhh,
      xg_enc, xg_dec, u1_lens, u2_lens, a_bf);

  // projection
  {
    dim3 g(153, 32);
    mfma_gemm_kernel<GM_PROJ><<<g, 256, 0, stream>>>(a_bf, wout_bf, out_b, out, nullptr, nullptr);
  }
}